// Round 1
// baseline (676.713 us; speedup 1.0000x reference)
//
#include <hip/hip_runtime.h>

#define NUM_GRAPHS 1024
#define BIN_BITS 10
#define BIN_SIZE (1 << BIN_BITS)      // 1024 nodes per bin
#define EB 8192                       // edges per binning block
#define STH 512                       // scatter threads (8 waves)
#define EPT 16                        // edges per thread in scatter (EB/STH)
#define ATH 1024                      // accum threads (= nodes per bin)

typedef int v4i __attribute__((ext_vector_type(4)));  // native vec for nt-load

// ---------------------------------------------------------------------------
// Prep: cursors to bin bases, zero pool accumulators, x -> packed bf16x4
// (8 B/node, 3.8 MB: fits every XCD L2 -> accum gather is cache-resident).
// ---------------------------------------------------------------------------
__device__ inline unsigned bf16_rn(float f) {
    unsigned u = __float_as_uint(f);
    return (u + 0x7FFFu + ((u >> 16) & 1u)) >> 16;
}
__global__ void prep_kernel(const float4* __restrict__ x, uint2* __restrict__ x16,
                            int N, int* __restrict__ cursor,
                            float* __restrict__ gsum, float* __restrict__ gcnt,
                            int cap) {
    int i = blockIdx.x * blockDim.x + threadIdx.x;
    if (i < 512) cursor[i] = i * cap;
    if (i < NUM_GRAPHS * 4) gsum[i] = 0.0f;
    if (i < NUM_GRAPHS) gcnt[i] = 0.0f;
    if (i < N) {
        float4 v = x[i];
        uint2 r;
        r.x = bf16_rn(v.x) | (bf16_rn(v.y) << 16);
        r.y = bf16_rn(v.z) | (bf16_rn(v.w) << 16);
        x16[i] = r;
    }
}

// ---------------------------------------------------------------------------
// bin_scatter v5 (UNCHANGED this round): rtn-atomic histogram pass,
// placement by plain LDS writes; placement co-writes sbin[slot]=bin so the
// flush needs NO binary search. packed = (dst_local << 19) | src.
// ---------------------------------------------------------------------------
__global__ void __launch_bounds__(STH) bin_scatter(const int* __restrict__ src,
                                                   const int* __restrict__ dst,
                                                   int* __restrict__ packed,
                                                   int* __restrict__ cursor,
                                                   int E, int cap, int nb) {
    __shared__ int shist[512];              // per-bin counts (rtn atomics)
    __shared__ int sprefix[513];            // prefix of counts
    __shared__ int sgbase[512];             // global base per bin
    __shared__ int spacked[EB];             // bin-sorted packed edges (32 KB)
    __shared__ unsigned short sbin[EB];     // bin id per sorted slot (16 KB)
    __shared__ int wsum[8];

    const int t = threadIdx.x;
    const int lane = t & 63;
    const int wave = t >> 6;
    const int b0 = blockIdx.x * EB;
    const int myBase = b0 + t * EPT;

    for (int j = t; j < 512; j += STH) shist[j] = 0;
    __syncthreads();

    // ---- pass A: rtn-atomic count; (bin,lpos)+packed stay in REGISTERS ----
    int pv[EPT];                   // packed edge values
    int bl[EPT];                   // (bin << 13) | lpos, or -1 if invalid
    const bool full = (myBase + EPT <= E);
    if (full) {
#pragma unroll
        for (int v = 0; v < EPT / 4; ++v) {
            int4 d = *(const int4*)(dst + myBase + v * 4);
            int4 s = *(const int4*)(src + myBase + v * 4);
            int bn, lp;
            bn = ((unsigned)d.x) >> BIN_BITS; lp = atomicAdd(&shist[bn], 1);
            pv[v * 4 + 0] = ((d.x & (BIN_SIZE - 1)) << 19) | s.x;
            bl[v * 4 + 0] = (bn << 13) | lp;
            bn = ((unsigned)d.y) >> BIN_BITS; lp = atomicAdd(&shist[bn], 1);
            pv[v * 4 + 1] = ((d.y & (BIN_SIZE - 1)) << 19) | s.y;
            bl[v * 4 + 1] = (bn << 13) | lp;
            bn = ((unsigned)d.z) >> BIN_BITS; lp = atomicAdd(&shist[bn], 1);
            pv[v * 4 + 2] = ((d.z & (BIN_SIZE - 1)) << 19) | s.z;
            bl[v * 4 + 2] = (bn << 13) | lp;
            bn = ((unsigned)d.w) >> BIN_BITS; lp = atomicAdd(&shist[bn], 1);
            pv[v * 4 + 3] = ((d.w & (BIN_SIZE - 1)) << 19) | s.w;
            bl[v * 4 + 3] = (bn << 13) | lp;
        }
    } else {
#pragma unroll
        for (int i = 0; i < EPT; ++i) {
            int e = myBase + i;
            bool ok = e < E;
            int d = ok ? dst[e] : 0;
            int s = ok ? src[e] : 0;
            int bn = ((unsigned)d) >> BIN_BITS;
            int lp = 0;
            if (ok) lp = atomicAdd(&shist[bn], 1);
            pv[i] = ((d & (BIN_SIZE - 1)) << 19) | s;
            bl[i] = ok ? ((bn << 13) | lp) : -1;
        }
    }
    __syncthreads();

    // ---- prefix scan of 512 counts (shfl within wave + cross-wave) ----
    {
        int v = shist[t];
        int inc = v;
#pragma unroll
        for (int off = 1; off < 64; off <<= 1) {
            int u = __shfl_up(inc, off);
            if (lane >= off) inc += u;
        }
        if (lane == 63) wsum[wave] = inc;
        __syncthreads();
        if (t == 0) {
            int acc = 0;
#pragma unroll
            for (int w = 0; w < 8; ++w) { int c = wsum[w]; wsum[w] = acc; acc += c; }
        }
        __syncthreads();
        sprefix[t + 1] = inc + wsum[wave];     // inclusive prefix at t
        if (t == 0) sprefix[0] = 0;
        if (t < nb && v > 0) sgbase[t] = atomicAdd(&cursor[t], v);
    }
    __syncthreads();

    // ---- pass B: place from registers — plain LDS writes, no atomics ----
    if (full) {
#pragma unroll
        for (int i = 0; i < EPT; ++i) {
            int bn = ((unsigned)bl[i]) >> 13;
            int lp = bl[i] & 0x1FFF;
            int idx = sprefix[bn] + lp;
            spacked[idx] = pv[i];
            sbin[idx] = (unsigned short)bn;
        }
    } else {
#pragma unroll
        for (int i = 0; i < EPT; ++i) {
            if (bl[i] >= 0) {
                int bn = ((unsigned)bl[i]) >> 13;
                int lp = bl[i] & 0x1FFF;
                int idx = sprefix[bn] + lp;
                spacked[idx] = pv[i];
                sbin[idx] = (unsigned short)bn;
            }
        }
    }
    __syncthreads();

    // ---- flush: table lookup instead of binary search ----
    int cnt = sprefix[nb < 512 ? nb : 512];
    int totE = E - b0; if (totE < 0) totE = 0;
    if (cnt > totE) cnt = totE;
    for (int j = t; j < cnt; j += STH) {
        int bn = sbin[j];
        int pos = sgbase[bn] + (j - sprefix[bn]);
        if (pos < (bn + 1) * cap)              // overflow guard (~28 sigma)
            __builtin_nontemporal_store(spacked[j], &packed[pos]);
    }
}

// ---------------------------------------------------------------------------
// Accum v6: DIRECT LDS f32 accumulation (ds_add_f32), no sort, no barriers
// in the main loop. Four 1024-float planes (16 KB) hold the bin aggregate;
// each edge does: nt 16B packed read -> bf16x4 gather x16[src] (L2-resident)
// -> 4x atomicAdd to LDS planes (bank = dl%32, uniform random -> ~2x
// conflict-free cost). Replaces histogram/prefix-scan/place/consume +
// 16 __syncthreads per block with a single stream loop + ONE barrier.
// Then MLP + pool as before.
// ---------------------------------------------------------------------------
__global__ void __launch_bounds__(ATH) bin_accum_mlp_pool(
        const float4* __restrict__ x,
        const uint2* __restrict__ x16,
        const int* __restrict__ packed,
        const int* __restrict__ cursor,
        const int* __restrict__ batch,
        const float* __restrict__ eps_p,
        const float* __restrict__ W1, const float* __restrict__ b1,
        const float* __restrict__ W2, const float* __restrict__ b2,
        float* __restrict__ gsum, float* __restrict__ gcnt,
        int N, int cap) {
    __shared__ float agg0[BIN_SIZE];    // 4 planes: bank = dl % 32 (random)
    __shared__ float agg1[BIN_SIZE];
    __shared__ float agg2[BIN_SIZE];
    __shared__ float agg3[BIN_SIZE];

    const int bin = blockIdx.x;
    const int t = threadIdx.x;

    agg0[t] = 0.0f; agg1[t] = 0.0f; agg2[t] = 0.0f; agg3[t] = 0.0f;
    __syncthreads();

    const int start = bin * cap;
    int end = cursor[bin];
    if (end > start + cap) end = start + cap;

    // ---- barrier-free stream: packed -> gather -> 4x ds_add_f32 ----
    for (int e = start + t * 4; e < end; e += ATH * 4) {
        if (e + 3 < end) {
            v4i p4 = __builtin_nontemporal_load((const v4i*)(packed + e));
#pragma unroll
            for (int k = 0; k < 4; ++k) {
                int p = (k == 0) ? p4.x : (k == 1) ? p4.y : (k == 2) ? p4.z : p4.w;
                int dl = ((unsigned)p) >> 19;
                uint2 v = x16[p & 0x7FFFF];
                atomicAdd(&agg0[dl], __uint_as_float(v.x << 16));
                atomicAdd(&agg1[dl], __uint_as_float(v.x & 0xFFFF0000u));
                atomicAdd(&agg2[dl], __uint_as_float(v.y << 16));
                atomicAdd(&agg3[dl], __uint_as_float(v.y & 0xFFFF0000u));
            }
        } else {
#pragma unroll
            for (int k = 0; k < 4; ++k) {
                if (e + k < end) {
                    int p = packed[e + k];
                    int dl = ((unsigned)p) >> 19;
                    uint2 v = x16[p & 0x7FFFF];
                    atomicAdd(&agg0[dl], __uint_as_float(v.x << 16));
                    atomicAdd(&agg1[dl], __uint_as_float(v.x & 0xFFFF0000u));
                    atomicAdd(&agg2[dl], __uint_as_float(v.y << 16));
                    atomicAdd(&agg3[dl], __uint_as_float(v.y & 0xFFFF0000u));
                }
            }
        }
    }
    __syncthreads();

    const float a0 = agg0[t], a1 = agg1[t], a2 = agg2[t], a3 = agg3[t];

    // ---- MLP + pool from LDS aggregate (self term in f32) ----
    int n = bin * BIN_SIZE + t;           // one node per thread
    bool valid = n < N;
    float o0 = 0.f, o1 = 0.f, o2 = 0.f, o3 = 0.f;
    int g = -1;
    if (valid) {
        float eps = eps_p[0];
        float4 xv = x[n];
        float h0 = (1.0f + eps) * xv.x + a0;
        float h1 = (1.0f + eps) * xv.y + a1;
        float h2 = (1.0f + eps) * xv.z + a2;
        float h3 = (1.0f + eps) * xv.w + a3;

        float tmp[16];
#pragma unroll
        for (int j = 0; j < 16; ++j) {
            float v = b1[j] + h0 * W1[j] + h1 * W1[16 + j] + h2 * W1[32 + j] + h3 * W1[48 + j];
            tmp[j] = v > 0.0f ? v : 0.0f;
        }
        float o[4];
#pragma unroll
        for (int j = 0; j < 4; ++j) {
            float v = b2[j];
#pragma unroll
            for (int k = 0; k < 16; ++k) v += tmp[k] * W2[k * 4 + j];
            o[j] = v > 0.0f ? v : 0.0f;
        }
        o0 = o[0]; o1 = o[1]; o2 = o[2]; o3 = o[3];
        g = batch[n];
    }

    // batch is sorted -> waves almost always graph-uniform
    int g0 = __shfl(g, 0);
    bool uni = __all(g == g0);
    if (uni && g0 >= 0) {
#pragma unroll
        for (int off = 32; off > 0; off >>= 1) {
            o0 += __shfl_down(o0, off);
            o1 += __shfl_down(o1, off);
            o2 += __shfl_down(o2, off);
            o3 += __shfl_down(o3, off);
        }
        if ((t & 63) == 0) {
            unsafeAtomicAdd(&gsum[(size_t)g0 * 4 + 0], o0);
            unsafeAtomicAdd(&gsum[(size_t)g0 * 4 + 1], o1);
            unsafeAtomicAdd(&gsum[(size_t)g0 * 4 + 2], o2);
            unsafeAtomicAdd(&gsum[(size_t)g0 * 4 + 3], o3);
            unsafeAtomicAdd(&gcnt[g0], 64.0f);
        }
    } else if (valid) {
        unsafeAtomicAdd(&gsum[(size_t)g * 4 + 0], o0);
        unsafeAtomicAdd(&gsum[(size_t)g * 4 + 1], o1);
        unsafeAtomicAdd(&gsum[(size_t)g * 4 + 2], o2);
        unsafeAtomicAdd(&gsum[(size_t)g * 4 + 3], o3);
        unsafeAtomicAdd(&gcnt[g], 1.0f);
    }
}

// ---------------------------------------------------------------------------
// pooled = sums / max(cnt,1); out = log_softmax per graph.
// ---------------------------------------------------------------------------
__global__ void pool_softmax_kernel(const float* __restrict__ gsum,
                                    const float* __restrict__ gcnt,
                                    float* __restrict__ out) {
    int g = blockIdx.x * blockDim.x + threadIdx.x;
    if (g >= NUM_GRAPHS) return;
    float c = fmaxf(gcnt[g], 1.0f);
    float p0 = gsum[g * 4 + 0] / c;
    float p1 = gsum[g * 4 + 1] / c;
    float p2 = gsum[g * 4 + 2] / c;
    float p3 = gsum[g * 4 + 3] / c;
    float m = fmaxf(fmaxf(p0, p1), fmaxf(p2, p3));
    float s = expf(p0 - m) + expf(p1 - m) + expf(p2 - m) + expf(p3 - m);
    float lse = m + logf(s);
    out[g * 4 + 0] = p0 - lse;
    out[g * 4 + 1] = p1 - lse;
    out[g * 4 + 2] = p2 - lse;
    out[g * 4 + 3] = p3 - lse;
}

// ---------------------------------------------------------------------------
// Fallback kernels (ws too small): direct atomic scatter + separate MLP/pool.
// ---------------------------------------------------------------------------
__global__ void edge_scatter_kernel(const float4* __restrict__ x,
                                    const int* __restrict__ src,
                                    const int* __restrict__ dst,
                                    float* __restrict__ agg,
                                    int E) {
    int t = blockIdx.x * blockDim.x + threadIdx.x;
    int e = t * 4;
    if (e + 3 < E) {
        int4 s = *(const int4*)(src + e);
        int4 d = *(const int4*)(dst + e);
        float4 xv;
        xv = x[s.x];
        unsafeAtomicAdd(&agg[(size_t)d.x * 4 + 0], xv.x);
        unsafeAtomicAdd(&agg[(size_t)d.x * 4 + 1], xv.y);
        unsafeAtomicAdd(&agg[(size_t)d.x * 4 + 2], xv.z);
        unsafeAtomicAdd(&agg[(size_t)d.x * 4 + 3], xv.w);
        xv = x[s.y];
        unsafeAtomicAdd(&agg[(size_t)d.y * 4 + 0], xv.x);
        unsafeAtomicAdd(&agg[(size_t)d.y * 4 + 1], xv.y);
        unsafeAtomicAdd(&agg[(size_t)d.y * 4 + 2], xv.z);
        unsafeAtomicAdd(&agg[(size_t)d.y * 4 + 3], xv.w);
        xv = x[s.z];
        unsafeAtomicAdd(&agg[(size_t)d.z * 4 + 0], xv.x);
        unsafeAtomicAdd(&agg[(size_t)d.z * 4 + 1], xv.y);
        unsafeAtomicAdd(&agg[(size_t)d.z * 4 + 2], xv.z);
        unsafeAtomicAdd(&agg[(size_t)d.z * 4 + 3], xv.w);
        xv = x[s.w];
        unsafeAtomicAdd(&agg[(size_t)d.w * 4 + 0], xv.x);
        unsafeAtomicAdd(&agg[(size_t)d.w * 4 + 1], xv.y);
        unsafeAtomicAdd(&agg[(size_t)d.w * 4 + 2], xv.z);
        unsafeAtomicAdd(&agg[(size_t)d.w * 4 + 3], xv.w);
    } else {
        for (int i = e; i < E; ++i) {
            int sv = src[i], dv = dst[i];
            float4 xv = x[sv];
            unsafeAtomicAdd(&agg[(size_t)dv * 4 + 0], xv.x);
            unsafeAtomicAdd(&agg[(size_t)dv * 4 + 1], xv.y);
            unsafeAtomicAdd(&agg[(size_t)dv * 4 + 2], xv.z);
            unsafeAtomicAdd(&agg[(size_t)dv * 4 + 3], xv.w);
        }
    }
}

__global__ void node_mlp_pool_kernel(const float4* __restrict__ x,
                                     const float4* __restrict__ agg,
                                     const int* __restrict__ batch,
                                     const float* __restrict__ eps_p,
                                     const float* __restrict__ W1,
                                     const float* __restrict__ b1,
                                     const float* __restrict__ W2,
                                     const float* __restrict__ b2,
                                     float* __restrict__ gsum,
                                     float* __restrict__ gcnt,
                                     int N) {
    int i = blockIdx.x * blockDim.x + threadIdx.x;
    bool valid = i < N;
    float o0 = 0.f, o1 = 0.f, o2 = 0.f, o3 = 0.f;
    int g = -1;
    if (valid) {
        float eps = eps_p[0];
        float4 xv = x[i];
        float4 av = agg[i];
        float h0 = (1.0f + eps) * xv.x + av.x;
        float h1 = (1.0f + eps) * xv.y + av.y;
        float h2 = (1.0f + eps) * xv.z + av.z;
        float h3 = (1.0f + eps) * xv.w + av.w;
        float tmp[16];
#pragma unroll
        for (int j = 0; j < 16; ++j) {
            float v = b1[j] + h0 * W1[j] + h1 * W1[16 + j] + h2 * W1[32 + j] + h3 * W1[48 + j];
            tmp[j] = v > 0.0f ? v : 0.0f;
        }
        float o[4];
#pragma unroll
        for (int j = 0; j < 4; ++j) {
            float v = b2[j];
#pragma unroll
            for (int k = 0; k < 16; ++k) v += tmp[k] * W2[k * 4 + j];
            o[j] = v > 0.0f ? v : 0.0f;
        }
        o0 = o[0]; o1 = o[1]; o2 = o[2]; o3 = o[3];
        g = batch[i];
    }
    int g0 = __shfl(g, 0);
    bool uni = __all(g == g0);
    if (uni && g0 >= 0) {
#pragma unroll
        for (int off = 32; off > 0; off >>= 1) {
            o0 += __shfl_down(o0, off);
            o1 += __shfl_down(o1, off);
            o2 += __shfl_down(o2, off);
            o3 += __shfl_down(o3, off);
        }
        if ((threadIdx.x & 63) == 0) {
            unsafeAtomicAdd(&gsum[(size_t)g0 * 4 + 0], o0);
            unsafeAtomicAdd(&gsum[(size_t)g0 * 4 + 1], o1);
            unsafeAtomicAdd(&gsum[(size_t)g0 * 4 + 2], o2);
            unsafeAtomicAdd(&gsum[(size_t)g0 * 4 + 3], o3);
            unsafeAtomicAdd(&gcnt[g0], 64.0f);
        }
    } else if (valid) {
        unsafeAtomicAdd(&gsum[(size_t)g * 4 + 0], o0);
        unsafeAtomicAdd(&gsum[(size_t)g * 4 + 1], o1);
        unsafeAtomicAdd(&gsum[(size_t)g * 4 + 2], o2);
        unsafeAtomicAdd(&gsum[(size_t)g * 4 + 3], o3);
        unsafeAtomicAdd(&gcnt[g], 1.0f);
    }
}

extern "C" void kernel_launch(void* const* d_in, const int* in_sizes, int n_in,
                              void* d_out, int out_size, void* d_ws, size_t ws_size,
                              hipStream_t stream) {
    const float* x     = (const float*)d_in[0];
    const int*   ei    = (const int*)d_in[1];
    const int*   batch = (const int*)d_in[2];
    const float* eps   = (const float*)d_in[3];
    const float* W1    = (const float*)d_in[4];
    const float* b1    = (const float*)d_in[5];
    const float* W2    = (const float*)d_in[6];
    const float* b2    = (const float*)d_in[7];

    const int N = in_sizes[0] / 4;
    const int E = in_sizes[1] / 2;
    const int* src = ei;
    const int* dst = ei + (size_t)E;

    const int nb = (N + BIN_SIZE - 1) >> BIN_BITS;   // 489 for N=500K
    const int epb = (E + nb - 1) / nb;
    int cap = epb + epb / 8 + 1024;                  // ~28 sigma headroom
    cap = (cap + 3) & ~3;                            // 16B-align chunk bases

    // Fast-path ws layout: x16 [2N] | packed [nb*cap] | cursor [512] |
    //                      gsum [G*4] | gcnt [G]      (4 B units)
    size_t x16_elems = ((size_t)2 * N + 3) & ~(size_t)3;
    size_t packed_elems = ((size_t)nb * cap + 3) & ~(size_t)3;
    size_t need = (x16_elems + packed_elems + 512 + NUM_GRAPHS * 5) * sizeof(float);

    if (nb <= 512 && N < (1 << 19) && need <= ws_size) {
        uint2* x16    = (uint2*)d_ws;
        int*   packed = (int*)d_ws + x16_elems;
        int*   cursor = packed + packed_elems;
        float* gsum   = (float*)(cursor + 512);
        float* gcnt   = gsum + (size_t)NUM_GRAPHS * 4;

        prep_kernel<<<(N + 511) / 512, 512, 0, stream>>>(
            (const float4*)x, x16, N, cursor, gsum, gcnt, cap);

        int nblocks_e = (E + EB - 1) / EB;
        bin_scatter<<<nblocks_e, STH, 0, stream>>>(src, dst, packed, cursor, E, cap, nb);

        bin_accum_mlp_pool<<<nb, ATH, 0, stream>>>(
            (const float4*)x, (const uint2*)x16, packed, cursor, batch, eps,
            W1, b1, W2, b2, gsum, gcnt, N, cap);

        pool_softmax_kernel<<<(NUM_GRAPHS + 255) / 256, 256, 0, stream>>>(
            gsum, gcnt, (float*)d_out);
    } else {
        float* agg  = (float*)d_ws;
        float* gsum = agg + (size_t)N * 4;
        float* gcnt = gsum + (size_t)NUM_GRAPHS * 4;
        size_t zero_bytes = ((size_t)N * 4 + NUM_GRAPHS * 5) * sizeof(float);
        (void)hipMemsetAsync(d_ws, 0, zero_bytes, stream);

        int e4 = (E + 3) / 4;
        edge_scatter_kernel<<<(e4 + 255) / 256, 256, 0, stream>>>(
            (const float4*)x, src, dst, agg, E);

        node_mlp_pool_kernel<<<(N + 255) / 256, 256, 0, stream>>>(
            (const float4*)x, (const float4*)agg, batch, eps, W1, b1, W2, b2,
            gsum, gcnt, N);

        pool_softmax_kernel<<<(NUM_GRAPHS + 255) / 256, 256, 0, stream>>>(
            gsum, gcnt, (float*)d_out);
    }
}

// Round 2
// 438.980 us; speedup vs baseline: 1.5416x; 1.5416x over previous
//
#include <hip/hip_runtime.h>

#define NUM_GRAPHS 1024
#define BIN_BITS 10
#define BIN_SIZE (1 << BIN_BITS)      // 1024 nodes per bin
#define EB 8192                       // edges per binning block
#define STH 512                       // scatter threads (8 waves)
#define EPT 16                        // edges per thread in scatter (EB/STH)
#define ACCTH 256                     // accum threads (4 waves)
#define ACCW 4                        // waves per accum block

typedef int v4i __attribute__((ext_vector_type(4)));  // native vec for nt-load

// ---------------------------------------------------------------------------
// Prep: cursors to bin bases, zero pool accumulators, x -> packed bf16x4
// (8 B/node, 3.8 MB: fits every XCD L2 -> accum gather is cache-resident).
// ---------------------------------------------------------------------------
__device__ inline unsigned bf16_rn(float f) {
    unsigned u = __float_as_uint(f);
    return (u + 0x7FFFu + ((u >> 16) & 1u)) >> 16;
}
__global__ void prep_kernel(const float4* __restrict__ x, uint2* __restrict__ x16,
                            int N, int* __restrict__ cursor,
                            float* __restrict__ gsum, float* __restrict__ gcnt,
                            int cap) {
    int i = blockIdx.x * blockDim.x + threadIdx.x;
    if (i < 512) cursor[i] = i * cap;
    if (i < NUM_GRAPHS * 4) gsum[i] = 0.0f;
    if (i < NUM_GRAPHS) gcnt[i] = 0.0f;
    if (i < N) {
        float4 v = x[i];
        uint2 r;
        r.x = bf16_rn(v.x) | (bf16_rn(v.y) << 16);
        r.y = bf16_rn(v.z) | (bf16_rn(v.w) << 16);
        x16[i] = r;
    }
}

// ---------------------------------------------------------------------------
// bin_scatter v5 (UNCHANGED): rtn-atomic histogram pass, placement by plain
// LDS writes; flush via sbin table. packed = (dst_local << 19) | src.
// ---------------------------------------------------------------------------
__global__ void __launch_bounds__(STH) bin_scatter(const int* __restrict__ src,
                                                   const int* __restrict__ dst,
                                                   int* __restrict__ packed,
                                                   int* __restrict__ cursor,
                                                   int E, int cap, int nb) {
    __shared__ int shist[512];              // per-bin counts (rtn atomics)
    __shared__ int sprefix[513];            // prefix of counts
    __shared__ int sgbase[512];             // global base per bin
    __shared__ int spacked[EB];             // bin-sorted packed edges (32 KB)
    __shared__ unsigned short sbin[EB];     // bin id per sorted slot (16 KB)
    __shared__ int wsum[8];

    const int t = threadIdx.x;
    const int lane = t & 63;
    const int wave = t >> 6;
    const int b0 = blockIdx.x * EB;
    const int myBase = b0 + t * EPT;

    for (int j = t; j < 512; j += STH) shist[j] = 0;
    __syncthreads();

    // ---- pass A: rtn-atomic count; (bin,lpos)+packed stay in REGISTERS ----
    int pv[EPT];                   // packed edge values
    int bl[EPT];                   // (bin << 13) | lpos, or -1 if invalid
    const bool full = (myBase + EPT <= E);
    if (full) {
#pragma unroll
        for (int v = 0; v < EPT / 4; ++v) {
            int4 d = *(const int4*)(dst + myBase + v * 4);
            int4 s = *(const int4*)(src + myBase + v * 4);
            int bn, lp;
            bn = ((unsigned)d.x) >> BIN_BITS; lp = atomicAdd(&shist[bn], 1);
            pv[v * 4 + 0] = ((d.x & (BIN_SIZE - 1)) << 19) | s.x;
            bl[v * 4 + 0] = (bn << 13) | lp;
            bn = ((unsigned)d.y) >> BIN_BITS; lp = atomicAdd(&shist[bn], 1);
            pv[v * 4 + 1] = ((d.y & (BIN_SIZE - 1)) << 19) | s.y;
            bl[v * 4 + 1] = (bn << 13) | lp;
            bn = ((unsigned)d.z) >> BIN_BITS; lp = atomicAdd(&shist[bn], 1);
            pv[v * 4 + 2] = ((d.z & (BIN_SIZE - 1)) << 19) | s.z;
            bl[v * 4 + 2] = (bn << 13) | lp;
            bn = ((unsigned)d.w) >> BIN_BITS; lp = atomicAdd(&shist[bn], 1);
            pv[v * 4 + 3] = ((d.w & (BIN_SIZE - 1)) << 19) | s.w;
            bl[v * 4 + 3] = (bn << 13) | lp;
        }
    } else {
#pragma unroll
        for (int i = 0; i < EPT; ++i) {
            int e = myBase + i;
            bool ok = e < E;
            int d = ok ? dst[e] : 0;
            int s = ok ? src[e] : 0;
            int bn = ((unsigned)d) >> BIN_BITS;
            int lp = 0;
            if (ok) lp = atomicAdd(&shist[bn], 1);
            pv[i] = ((d & (BIN_SIZE - 1)) << 19) | s;
            bl[i] = ok ? ((bn << 13) | lp) : -1;
        }
    }
    __syncthreads();

    // ---- prefix scan of 512 counts (shfl within wave + cross-wave) ----
    {
        int v = shist[t];
        int inc = v;
#pragma unroll
        for (int off = 1; off < 64; off <<= 1) {
            int u = __shfl_up(inc, off);
            if (lane >= off) inc += u;
        }
        if (lane == 63) wsum[wave] = inc;
        __syncthreads();
        if (t == 0) {
            int acc = 0;
#pragma unroll
            for (int w = 0; w < 8; ++w) { int c = wsum[w]; wsum[w] = acc; acc += c; }
        }
        __syncthreads();
        sprefix[t + 1] = inc + wsum[wave];     // inclusive prefix at t
        if (t == 0) sprefix[0] = 0;
        if (t < nb && v > 0) sgbase[t] = atomicAdd(&cursor[t], v);
    }
    __syncthreads();

    // ---- pass B: place from registers — plain LDS writes, no atomics ----
    if (full) {
#pragma unroll
        for (int i = 0; i < EPT; ++i) {
            int bn = ((unsigned)bl[i]) >> 13;
            int lp = bl[i] & 0x1FFF;
            int idx = sprefix[bn] + lp;
            spacked[idx] = pv[i];
            sbin[idx] = (unsigned short)bn;
        }
    } else {
#pragma unroll
        for (int i = 0; i < EPT; ++i) {
            if (bl[i] >= 0) {
                int bn = ((unsigned)bl[i]) >> 13;
                int lp = bl[i] & 0x1FFF;
                int idx = sprefix[bn] + lp;
                spacked[idx] = pv[i];
                sbin[idx] = (unsigned short)bn;
            }
        }
    }
    __syncthreads();

    // ---- flush: table lookup instead of binary search ----
    int cnt = sprefix[nb < 512 ? nb : 512];
    int totE = E - b0; if (totE < 0) totE = 0;
    if (cnt > totE) cnt = totE;
    for (int j = t; j < cnt; j += STH) {
        int bn = sbin[j];
        int pos = sgbase[bn] + (j - sprefix[bn]);
        if (pos < (bn + 1) * cap)              // overflow guard (~28 sigma)
            __builtin_nontemporal_store(spacked[j], &packed[pos]);
    }
}

// ---------------------------------------------------------------------------
// Accum v7: ZERO-ATOMIC scatter-add. Post-mortem of v6 measured LDS atomics
// at ~3.8 cy/lane-op (serial path, conflicts irrelevant) -> any >=1-atomic-
// per-edge scheme floors near 100 us. v7 removes atomics:
//  - per-WAVE private planes [4][1024][4] f32 = 64 KB LDS (cross-wave races
//    impossible), 256-thread blocks, 2 blocks/CU.
//  - intra-wave same-dl collisions resolved in REGISTERS: 11-ballot match
//    mask -> rank within group -> plain b128 read/add/write RMW executed in
//    rank-ordered passes (while __any(rank>=pass); groups ~always singletons
//    -> 1 pass). Same-wave LDS ops execute in program order, so pass p's
//    write is visible to pass p+1's read.
//  - no barriers in the edge loop; then reduce 4 planes + MLP + pool.
// ---------------------------------------------------------------------------
__global__ void __launch_bounds__(ACCTH) bin_accum_mlp_pool(
        const float4* __restrict__ x,
        const uint2* __restrict__ x16,
        const int* __restrict__ packed,
        const int* __restrict__ cursor,
        const int* __restrict__ batch,
        const float* __restrict__ eps_p,
        const float* __restrict__ W1, const float* __restrict__ b1,
        const float* __restrict__ W2, const float* __restrict__ b2,
        float* __restrict__ gsum, float* __restrict__ gcnt,
        int N, int cap) {
    __shared__ float planes[ACCW][BIN_SIZE][4];   // 64 KB, per-wave private

    const int bin = blockIdx.x;
    const int t = threadIdx.x;
    const int lane = t & 63;
    const int wave = t >> 6;

    // zero planes: 4096 float4s / 256 threads = 16 each
    {
        float4* pz = (float4*)&planes[0][0][0];
        float4 z; z.x = 0.f; z.y = 0.f; z.z = 0.f; z.w = 0.f;
#pragma unroll
        for (int i = 0; i < 16; ++i) pz[t + i * ACCTH] = z;
    }
    __syncthreads();

    const int start = bin * cap;
    int end = cursor[bin];
    if (end > start + cap) end = start + cap;
    int cnt = end - start; if (cnt < 0) cnt = 0;

    // contiguous per-wave segments, 16B-aligned bases
    int seg = ((cnt + ACCW - 1) / ACCW + 3) & ~3;
    int s0 = start + wave * seg;
    int s1 = s0 + seg; if (s1 > end) s1 = end;

    // one edge per lane per round; 4 rounds per 16B packed load
    for (int base = s0; base < s1; base += 256) {
        int b = base + lane * 4;
        int pe[4];
        if (b + 3 < s1) {
            v4i p4 = __builtin_nontemporal_load((const v4i*)(packed + b));
            pe[0] = p4.x; pe[1] = p4.y; pe[2] = p4.z; pe[3] = p4.w;
        } else {
            pe[0] = (b + 0 < s1) ? packed[b + 0] : -1;
            pe[1] = (b + 1 < s1) ? packed[b + 1] : -1;
            pe[2] = (b + 2 < s1) ? packed[b + 2] : -1;
            pe[3] = (b + 3 < s1) ? packed[b + 3] : -1;
        }
        // issue all 4 gathers up-front (L2-resident x16); invalid -> masked
        // index 0x7FFFF still lands inside ws (packed region), value unused.
        uint2 g[4];
#pragma unroll
        for (int k = 0; k < 4; ++k) g[k] = x16[pe[k] & 0x7FFFF];

#pragma unroll
        for (int k = 0; k < 4; ++k) {
            int p = pe[k];
            bool ok = p >= 0;
            int dl = (((unsigned)p) >> 19) & (BIN_SIZE - 1);
            // ---- 11-ballot match: lanes sharing my dl (valid lanes only) --
            unsigned long long m;
            {
                unsigned long long bv = __ballot(ok);
                m = ok ? bv : ~bv;
#pragma unroll
                for (int bb = 0; bb < BIN_BITS; ++bb) {
                    unsigned long long bl_ = __ballot((dl >> bb) & 1);
                    m &= ((dl >> bb) & 1) ? bl_ : ~bl_;
                }
            }
            int rank = ok ? (int)__popcll(m & ((1ull << lane) - 1ull)) : -1;

            float v0 = __uint_as_float(g[k].x << 16);
            float v1 = __uint_as_float(g[k].x & 0xFFFF0000u);
            float v2 = __uint_as_float(g[k].y << 16);
            float v3 = __uint_as_float(g[k].y & 0xFFFF0000u);
            float4* pp = (float4*)&planes[wave][dl][0];
            // rank-ordered RMW passes; singleton groups -> exactly 1 pass
            for (int pass = 0; __any(rank >= pass); ++pass) {
                if (rank == pass) {
                    float4 a = *pp;
                    a.x += v0; a.y += v1; a.z += v2; a.w += v3;
                    *pp = a;
                }
            }
        }
    }
    __syncthreads();

    // ---- reduce 4 planes + MLP + pool; 4 node-batches of 256 ----
    const float eps = eps_p[0];
    for (int half = 0; half < 4; ++half) {
        int node = t + half * ACCTH;           // 0..1023
        float4 a = *(const float4*)&planes[0][node][0];
#pragma unroll
        for (int w = 1; w < ACCW; ++w) {
            float4 bq = *(const float4*)&planes[w][node][0];
            a.x += bq.x; a.y += bq.y; a.z += bq.z; a.w += bq.w;
        }

        int n = bin * BIN_SIZE + node;         // one node per thread
        bool valid = n < N;
        float o0 = 0.f, o1 = 0.f, o2 = 0.f, o3 = 0.f;
        int g = -1;
        if (valid) {
            float4 xv = x[n];
            float h0 = (1.0f + eps) * xv.x + a.x;
            float h1 = (1.0f + eps) * xv.y + a.y;
            float h2 = (1.0f + eps) * xv.z + a.z;
            float h3 = (1.0f + eps) * xv.w + a.w;

            float tmp[16];
#pragma unroll
            for (int j = 0; j < 16; ++j) {
                float v = b1[j] + h0 * W1[j] + h1 * W1[16 + j] + h2 * W1[32 + j] + h3 * W1[48 + j];
                tmp[j] = v > 0.0f ? v : 0.0f;
            }
            float o[4];
#pragma unroll
            for (int j = 0; j < 4; ++j) {
                float v = b2[j];
#pragma unroll
                for (int k = 0; k < 16; ++k) v += tmp[k] * W2[k * 4 + j];
                o[j] = v > 0.0f ? v : 0.0f;
            }
            o0 = o[0]; o1 = o[1]; o2 = o[2]; o3 = o[3];
            g = batch[n];
        }

        // batch is sorted -> waves almost always graph-uniform
        int g0 = __shfl(g, 0);
        bool uni = __all(g == g0);
        if (uni && g0 >= 0) {
#pragma unroll
            for (int off = 32; off > 0; off >>= 1) {
                o0 += __shfl_down(o0, off);
                o1 += __shfl_down(o1, off);
                o2 += __shfl_down(o2, off);
                o3 += __shfl_down(o3, off);
            }
            if (lane == 0) {
                unsafeAtomicAdd(&gsum[(size_t)g0 * 4 + 0], o0);
                unsafeAtomicAdd(&gsum[(size_t)g0 * 4 + 1], o1);
                unsafeAtomicAdd(&gsum[(size_t)g0 * 4 + 2], o2);
                unsafeAtomicAdd(&gsum[(size_t)g0 * 4 + 3], o3);
                unsafeAtomicAdd(&gcnt[g0], 64.0f);
            }
        } else if (valid) {
            unsafeAtomicAdd(&gsum[(size_t)g * 4 + 0], o0);
            unsafeAtomicAdd(&gsum[(size_t)g * 4 + 1], o1);
            unsafeAtomicAdd(&gsum[(size_t)g * 4 + 2], o2);
            unsafeAtomicAdd(&gsum[(size_t)g * 4 + 3], o3);
            unsafeAtomicAdd(&gcnt[g], 1.0f);
        }
    }
}

// ---------------------------------------------------------------------------
// pooled = sums / max(cnt,1); out = log_softmax per graph.
// ---------------------------------------------------------------------------
__global__ void pool_softmax_kernel(const float* __restrict__ gsum,
                                    const float* __restrict__ gcnt,
                                    float* __restrict__ out) {
    int g = blockIdx.x * blockDim.x + threadIdx.x;
    if (g >= NUM_GRAPHS) return;
    float c = fmaxf(gcnt[g], 1.0f);
    float p0 = gsum[g * 4 + 0] / c;
    float p1 = gsum[g * 4 + 1] / c;
    float p2 = gsum[g * 4 + 2] / c;
    float p3 = gsum[g * 4 + 3] / c;
    float m = fmaxf(fmaxf(p0, p1), fmaxf(p2, p3));
    float s = expf(p0 - m) + expf(p1 - m) + expf(p2 - m) + expf(p3 - m);
    float lse = m + logf(s);
    out[g * 4 + 0] = p0 - lse;
    out[g * 4 + 1] = p1 - lse;
    out[g * 4 + 2] = p2 - lse;
    out[g * 4 + 3] = p3 - lse;
}

// ---------------------------------------------------------------------------
// Fallback kernels (ws too small): direct atomic scatter + separate MLP/pool.
// ---------------------------------------------------------------------------
__global__ void edge_scatter_kernel(const float4* __restrict__ x,
                                    const int* __restrict__ src,
                                    const int* __restrict__ dst,
                                    float* __restrict__ agg,
                                    int E) {
    int t = blockIdx.x * blockDim.x + threadIdx.x;
    int e = t * 4;
    if (e + 3 < E) {
        int4 s = *(const int4*)(src + e);
        int4 d = *(const int4*)(dst + e);
        float4 xv;
        xv = x[s.x];
        unsafeAtomicAdd(&agg[(size_t)d.x * 4 + 0], xv.x);
        unsafeAtomicAdd(&agg[(size_t)d.x * 4 + 1], xv.y);
        unsafeAtomicAdd(&agg[(size_t)d.x * 4 + 2], xv.z);
        unsafeAtomicAdd(&agg[(size_t)d.x * 4 + 3], xv.w);
        xv = x[s.y];
        unsafeAtomicAdd(&agg[(size_t)d.y * 4 + 0], xv.x);
        unsafeAtomicAdd(&agg[(size_t)d.y * 4 + 1], xv.y);
        unsafeAtomicAdd(&agg[(size_t)d.y * 4 + 2], xv.z);
        unsafeAtomicAdd(&agg[(size_t)d.y * 4 + 3], xv.w);
        xv = x[s.z];
        unsafeAtomicAdd(&agg[(size_t)d.z * 4 + 0], xv.x);
        unsafeAtomicAdd(&agg[(size_t)d.z * 4 + 1], xv.y);
        unsafeAtomicAdd(&agg[(size_t)d.z * 4 + 2], xv.z);
        unsafeAtomicAdd(&agg[(size_t)d.z * 4 + 3], xv.w);
        xv = x[s.w];
        unsafeAtomicAdd(&agg[(size_t)d.w * 4 + 0], xv.x);
        unsafeAtomicAdd(&agg[(size_t)d.w * 4 + 1], xv.y);
        unsafeAtomicAdd(&agg[(size_t)d.w * 4 + 2], xv.z);
        unsafeAtomicAdd(&agg[(size_t)d.w * 4 + 3], xv.w);
    } else {
        for (int i = e; i < E; ++i) {
            int sv = src[i], dv = dst[i];
            float4 xv = x[sv];
            unsafeAtomicAdd(&agg[(size_t)dv * 4 + 0], xv.x);
            unsafeAtomicAdd(&agg[(size_t)dv * 4 + 1], xv.y);
            unsafeAtomicAdd(&agg[(size_t)dv * 4 + 2], xv.z);
            unsafeAtomicAdd(&agg[(size_t)dv * 4 + 3], xv.w);
        }
    }
}

__global__ void node_mlp_pool_kernel(const float4* __restrict__ x,
                                     const float4* __restrict__ agg,
                                     const int* __restrict__ batch,
                                     const float* __restrict__ eps_p,
                                     const float* __restrict__ W1,
                                     const float* __restrict__ b1,
                                     const float* __restrict__ W2,
                                     const float* __restrict__ b2,
                                     float* __restrict__ gsum,
                                     float* __restrict__ gcnt,
                                     int N) {
    int i = blockIdx.x * blockDim.x + threadIdx.x;
    bool valid = i < N;
    float o0 = 0.f, o1 = 0.f, o2 = 0.f, o3 = 0.f;
    int g = -1;
    if (valid) {
        float eps = eps_p[0];
        float4 xv = x[i];
        float4 av = agg[i];
        float h0 = (1.0f + eps) * xv.x + av.x;
        float h1 = (1.0f + eps) * xv.y + av.y;
        float h2 = (1.0f + eps) * xv.z + av.z;
        float h3 = (1.0f + eps) * xv.w + av.w;
        float tmp[16];
#pragma unroll
        for (int j = 0; j < 16; ++j) {
            float v = b1[j] + h0 * W1[j] + h1 * W1[16 + j] + h2 * W1[32 + j] + h3 * W1[48 + j];
            tmp[j] = v > 0.0f ? v : 0.0f;
        }
        float o[4];
#pragma unroll
        for (int j = 0; j < 4; ++j) {
            float v = b2[j];
#pragma unroll
            for (int k = 0; k < 16; ++k) v += tmp[k] * W2[k * 4 + j];
            o[j] = v > 0.0f ? v : 0.0f;
        }
        o0 = o[0]; o1 = o[1]; o2 = o[2]; o3 = o[3];
        g = batch[i];
    }
    int g0 = __shfl(g, 0);
    bool uni = __all(g == g0);
    if (uni && g0 >= 0) {
#pragma unroll
        for (int off = 32; off > 0; off >>= 1) {
            o0 += __shfl_down(o0, off);
            o1 += __shfl_down(o1, off);
            o2 += __shfl_down(o2, off);
            o3 += __shfl_down(o3, off);
        }
        if ((threadIdx.x & 63) == 0) {
            unsafeAtomicAdd(&gsum[(size_t)g0 * 4 + 0], o0);
            unsafeAtomicAdd(&gsum[(size_t)g0 * 4 + 1], o1);
            unsafeAtomicAdd(&gsum[(size_t)g0 * 4 + 2], o2);
            unsafeAtomicAdd(&gsum[(size_t)g0 * 4 + 3], o3);
            unsafeAtomicAdd(&gcnt[g0], 64.0f);
        }
    } else if (valid) {
        unsafeAtomicAdd(&gsum[(size_t)g * 4 + 0], o0);
        unsafeAtomicAdd(&gsum[(size_t)g * 4 + 1], o1);
        unsafeAtomicAdd(&gsum[(size_t)g * 4 + 2], o2);
        unsafeAtomicAdd(&gsum[(size_t)g * 4 + 3], o3);
        unsafeAtomicAdd(&gcnt[g], 1.0f);
    }
}

extern "C" void kernel_launch(void* const* d_in, const int* in_sizes, int n_in,
                              void* d_out, int out_size, void* d_ws, size_t ws_size,
                              hipStream_t stream) {
    const float* x     = (const float*)d_in[0];
    const int*   ei    = (const int*)d_in[1];
    const int*   batch = (const int*)d_in[2];
    const float* eps   = (const float*)d_in[3];
    const float* W1    = (const float*)d_in[4];
    const float* b1    = (const float*)d_in[5];
    const float* W2    = (const float*)d_in[6];
    const float* b2    = (const float*)d_in[7];

    const int N = in_sizes[0] / 4;
    const int E = in_sizes[1] / 2;
    const int* src = ei;
    const int* dst = ei + (size_t)E;

    const int nb = (N + BIN_SIZE - 1) >> BIN_BITS;   // 489 for N=500K
    const int epb = (E + nb - 1) / nb;
    int cap = epb + epb / 8 + 1024;                  // ~28 sigma headroom
    cap = (cap + 3) & ~3;                            // 16B-align chunk bases

    // Fast-path ws layout: x16 [2N] | packed [nb*cap] | cursor [512] |
    //                      gsum [G*4] | gcnt [G]      (4 B units)
    size_t x16_elems = ((size_t)2 * N + 3) & ~(size_t)3;
    size_t packed_elems = ((size_t)nb * cap + 3) & ~(size_t)3;
    size_t need = (x16_elems + packed_elems + 512 + NUM_GRAPHS * 5) * sizeof(float);

    if (nb <= 512 && N < (1 << 19) && need <= ws_size) {
        uint2* x16    = (uint2*)d_ws;
        int*   packed = (int*)d_ws + x16_elems;
        int*   cursor = packed + packed_elems;
        float* gsum   = (float*)(cursor + 512);
        float* gcnt   = gsum + (size_t)NUM_GRAPHS * 4;

        prep_kernel<<<(N + 511) / 512, 512, 0, stream>>>(
            (const float4*)x, x16, N, cursor, gsum, gcnt, cap);

        int nblocks_e = (E + EB - 1) / EB;
        bin_scatter<<<nblocks_e, STH, 0, stream>>>(src, dst, packed, cursor, E, cap, nb);

        bin_accum_mlp_pool<<<nb, ACCTH, 0, stream>>>(
            (const float4*)x, (const uint2*)x16, packed, cursor, batch, eps,
            W1, b1, W2, b2, gsum, gcnt, N, cap);

        pool_softmax_kernel<<<(NUM_GRAPHS + 255) / 256, 256, 0, stream>>>(
            gsum, gcnt, (float*)d_out);
    } else {
        float* agg  = (float*)d_ws;
        float* gsum = agg + (size_t)N * 4;
        float* gcnt = gsum + (size_t)NUM_GRAPHS * 4;
        size_t zero_bytes = ((size_t)N * 4 + NUM_GRAPHS * 5) * sizeof(float);
        (void)hipMemsetAsync(d_ws, 0, zero_bytes, stream);

        int e4 = (E + 3) / 4;
        edge_scatter_kernel<<<(e4 + 255) / 256, 256, 0, stream>>>(
            (const float4*)x, src, dst, agg, E);

        node_mlp_pool_kernel<<<(N + 255) / 256, 256, 0, stream>>>(
            (const float4*)x, (const float4*)agg, batch, eps, W1, b1, W2, b2,
            gsum, gcnt, N);

        pool_softmax_kernel<<<(NUM_GRAPHS + 255) / 256, 256, 0, stream>>>(
            gsum, gcnt, (float*)d_out);
    }
}